// Round 2
// baseline (653.382 us; speedup 1.0000x reference)
//
#include <hip/hip_runtime.h>
#include <stdint.h>

#define S_LEN 2048
#define NB 32
#define NE 512
#define NU 512
#define NP 256

typedef __bf16 bf16;
typedef __bf16 bf16x8 __attribute__((ext_vector_type(8)));
typedef __bf16 bf16x4 __attribute__((ext_vector_type(4)));
typedef float f32x4 __attribute__((ext_vector_type(4)));
typedef float f32x8 __attribute__((ext_vector_type(8)));

// Design note (R2): all MFMA operands are loaded per-lane DIRECTLY from
// global memory as 16 contiguous bytes (row = lane&15, k-block = lane>>4).
// A and B fragments share the same lane layout for 16x16x32, and the MFMA
// result is invariant to any k-permutation applied to both operands, so
// this is correct regardless of the exact HW k-mapping. Only the C/D
// layout (col=lane&15, row=(lane>>4)*4+q; HW-verified) is relied upon.

// ---------------- kernel 0a: seq[b][s][e] fp32 -> seqtH[b][e][s] bf16(hi) --
__global__ __launch_bounds__(256) void k_prep(
    const float* __restrict__ seq, bf16* __restrict__ tHi)
{
    __shared__ float tile[64][65];
    const int bid = blockIdx.x;
    const int b = bid >> 8;
    const int r = bid & 255;
    const int s0 = (r & 31) << 6;
    const int e0 = (r >> 5) << 6;
    const int t = threadIdx.x;
    const int tx = t & 15, ty = t >> 4;
    const float* src = seq + ((size_t)b * S_LEN + s0) * NE + e0;
#pragma unroll
    for (int i = 0; i < 4; ++i) {
        const int row = ty + i * 16;
        const float4 v = *(const float4*)(src + (size_t)row * NE + tx * 4);
        tile[row][tx * 4 + 0] = v.x; tile[row][tx * 4 + 1] = v.y;
        tile[row][tx * 4 + 2] = v.z; tile[row][tx * 4 + 3] = v.w;
    }
    __syncthreads();
    const int sx = t & 7, ey = t >> 3;
#pragma unroll
    for (int jj = 0; jj < 2; ++jj) {
        const int er = ey + jj * 32;
        bf16x8 oh;
#pragma unroll
        for (int q = 0; q < 8; ++q) oh[q] = (bf16)tile[sx * 8 + q][er];
        *(bf16x8*)(tHi + ((size_t)b * NE + e0 + er) * S_LEN + s0 + sx * 8) = oh;
    }
}

// ---------------- kernel 0b: w1 fp32 -> bf16 hi/lo --------------------------
__global__ __launch_bounds__(256) void k_wconv(
    const float* __restrict__ w1, bf16* __restrict__ wHi, bf16* __restrict__ wLo)
{
    const int i = (blockIdx.x * 256 + threadIdx.x) * 4;
    const float4 v = *(const float4*)(w1 + i);
    const float vv[4] = {v.x, v.y, v.z, v.w};
    bf16x4 oh, ol;
#pragma unroll
    for (int q = 0; q < 4; ++q) {
        const bf16 hb = (bf16)vv[q];
        oh[q] = hb;
        ol[q] = (bf16)(vv[q] - (float)hb);
    }
    *(bf16x4*)(wHi + i) = oh;
    *(bf16x4*)(wLo + i) = ol;
}

// ---------------- kernel 1: GEMM1 + silu + logits + softmax -----------------
// A = seq fp32 [row][e] split hi/lo in regs; B = w1 hi/lo bf16 [u][e].
// block: 128 rows; wave wid owns rows wid*32..+31 (2 m-tiles), loops 4 u-panels.
__global__ __launch_bounds__(256, 2) void k_gemm1(
    const float* __restrict__ seq,
    const bf16* __restrict__ w1H, const bf16* __restrict__ w1L,
    const float* __restrict__ b1v, const float* __restrict__ w2,
    const float* __restrict__ b2v, float* __restrict__ actions)
{
    const int tid = threadIdx.x;
    const int wid = tid >> 6;
    const int lane = tid & 63;
    const int lr = lane & 15, lg = lane >> 4;
    const int m0 = blockIdx.x << 7;

    const float* arow0 = seq + (size_t)(m0 + wid * 32 + lr) * NE + lg * 8;
    const float* arow1 = arow0 + 16 * NE;

    float plog[3][2][4];
#pragma unroll
    for (int a = 0; a < 3; ++a)
#pragma unroll
        for (int i = 0; i < 2; ++i)
#pragma unroll
            for (int q = 0; q < 4; ++q) plog[a][i][q] = 0.f;

    for (int p = 0; p < 4; ++p) {
        const int u0 = p << 7;
        const bf16* bhp = w1H + (size_t)(u0 + lr) * NE + lg * 8;
        const bf16* blp = w1L + (size_t)(u0 + lr) * NE + lg * 8;
        f32x4 acc[2][8];
#pragma unroll
        for (int i = 0; i < 2; ++i)
#pragma unroll
            for (int j = 0; j < 8; ++j) acc[i][j] = (f32x4)(0.f);

        for (int kt = 0; kt < 16; ++kt) {
            const int k0 = kt * 32;
            bf16x8 Ah[2], Al[2];
            const f32x8 f0 = *(const f32x8*)(arow0 + k0);
            const f32x8 f1 = *(const f32x8*)(arow1 + k0);
#pragma unroll
            for (int q = 0; q < 8; ++q) {
                const bf16 h0 = (bf16)f0[q];
                Ah[0][q] = h0; Al[0][q] = (bf16)(f0[q] - (float)h0);
                const bf16 h1 = (bf16)f1[q];
                Ah[1][q] = h1; Al[1][q] = (bf16)(f1[q] - (float)h1);
            }
#pragma unroll
            for (int j = 0; j < 8; ++j) {
                const bf16x8 Bh = *(const bf16x8*)(bhp + (size_t)j * 16 * NE + k0);
                const bf16x8 Bl = *(const bf16x8*)(blp + (size_t)j * 16 * NE + k0);
                acc[0][j] = __builtin_amdgcn_mfma_f32_16x16x32_bf16(Ah[0], Bh, acc[0][j], 0, 0, 0);
                acc[0][j] = __builtin_amdgcn_mfma_f32_16x16x32_bf16(Ah[0], Bl, acc[0][j], 0, 0, 0);
                acc[0][j] = __builtin_amdgcn_mfma_f32_16x16x32_bf16(Al[0], Bh, acc[0][j], 0, 0, 0);
                acc[1][j] = __builtin_amdgcn_mfma_f32_16x16x32_bf16(Ah[1], Bh, acc[1][j], 0, 0, 0);
                acc[1][j] = __builtin_amdgcn_mfma_f32_16x16x32_bf16(Ah[1], Bl, acc[1][j], 0, 0, 0);
                acc[1][j] = __builtin_amdgcn_mfma_f32_16x16x32_bf16(Al[1], Bh, acc[1][j], 0, 0, 0);
            }
        }
        // epilogue: silu + partial logits (this wave covers all 128 cols of panel)
#pragma unroll
        for (int j = 0; j < 8; ++j) {
            const int col = u0 + j * 16 + lr;
            const float b1c = b1v[col];
            const float w20 = w2[col], w21 = w2[NU + col], w22 = w2[2 * NU + col];
#pragma unroll
            for (int i = 0; i < 2; ++i)
#pragma unroll
                for (int q = 0; q < 4; ++q) {
                    const float x = acc[i][j][q] + b1c;
                    const float hgate = x / (1.f + __expf(-x));
                    plog[0][i][q] = fmaf(hgate, w20, plog[0][i][q]);
                    plog[1][i][q] = fmaf(hgate, w21, plog[1][i][q]);
                    plog[2][i][q] = fmaf(hgate, w22, plog[2][i][q]);
                }
        }
    }
    // butterfly reduce over the 16 col-lanes (bits 0..3 of lane)
#pragma unroll
    for (int m = 1; m < 16; m <<= 1) {
#pragma unroll
        for (int a = 0; a < 3; ++a)
#pragma unroll
            for (int i = 0; i < 2; ++i)
#pragma unroll
                for (int q = 0; q < 4; ++q)
                    plog[a][i][q] += __shfl_xor(plog[a][i][q], m);
    }
    const float bb0 = b2v[0], bb1 = b2v[1], bb2 = b2v[2];
    if (lr == 0) {
#pragma unroll
        for (int i = 0; i < 2; ++i)
#pragma unroll
            for (int q = 0; q < 4; ++q) {
                const int row = m0 + wid * 32 + i * 16 + lg * 4 + q;
                const float l0 = plog[0][i][q] + bb0;
                const float l1 = plog[1][i][q] + bb1;
                const float l2 = plog[2][i][q] + bb2;
                const float mx = fmaxf(l0, fmaxf(l1, l2));
                const float e0 = __expf(l0 - mx), e1 = __expf(l1 - mx), e2 = __expf(l2 - mx);
                const float inv = 1.f / (e0 + e1 + e2);
                *(float4*)(actions + (size_t)row * 4) = make_float4(e0 * inv, e1 * inv, e2 * inv, 0.f);
            }
    }
}

// ---------------- kernel 2: sequential scan, writes wsT[b][p][t] bf16 -------
// one wave per batch; lane = (h = lane>>2, wq = lane&3) owns w = wq*4..+3.
// 8-step register frags give 16B coalesced-row stores in the [p][t] layout.
__global__ __launch_bounds__(64) void k_scan(
    const float* __restrict__ actions, bf16* __restrict__ wsT)
{
    const int b = blockIdx.x;
    const int lane = threadIdx.x;
    const int h = lane >> 2;
    const int wq = lane & 3;
    float T0 = 0.f, T1 = 0.f, T2 = 0.f, T3 = 0.f;
    if (lane == 3) T3 = 1.f;          // T[b][0][15] = 1 (h=0 -> lanes 0..3, w=15 -> wq=3 cell 3)
    float rs = (h == 0) ? 1.f : 0.f;  // rs replicated across the 4 lanes of a row
    const float4* act = (const float4*)actions + (size_t)b * S_LEN;
    bf16* ob = wsT + ((size_t)b * NP + lane * 4) * S_LEN;  // row p = lane*4

    for (int s4 = 0; s4 < S_LEN; s4 += 8) {
        const int tbase = S_LEN - 8 - s4;
        bf16x8 fr0, fr1, fr2, fr3;
#pragma unroll
        for (int u = 0; u < 8; ++u) {
            const float4 Av = act[tbase + 7 - u];   // step sv=s4+u uses actions[S-1-sv]
            const float a0 = Av.x, a1 = Av.y, a2 = Av.z;
            const float s01 = a0 + a1;
            const int fi = 7 - u;                    // t = tbase + fi
            fr0[fi] = (bf16)(s01 * T0);
            fr1[fi] = (bf16)(s01 * T1);
            fr2[fi] = (bf16)(s01 * T2);
            fr3[fi] = (bf16)(s01 * T3);
            const float rsp = __shfl_up(rs, 4);              // rs[h-1]
            const float sums = (h == 0) ? 0.f : a1 * rsp;
            const float nT0 = __shfl_down(T0, 1);            // T[w+1] for cell 3
            const float q1 = a0 * T1, q2 = a0 * T2, q3 = a0 * T3;
            const float qe = (wq == 3) ? sums : a0 * nT0;
            T0 = fmaf(a2, T0, q1);
            T1 = fmaf(a2, T1, q2);
            T2 = fmaf(a2, T2, q3);
            T3 = fmaf(a2, T3, qe);
            rs = fmaf(a0 + a2, rs, sums);
        }
        *(bf16x8*)(ob + (size_t)0 * S_LEN + tbase) = fr0;
        *(bf16x8*)(ob + (size_t)1 * S_LEN + tbase) = fr1;
        *(bf16x8*)(ob + (size_t)2 * S_LEN + tbase) = fr2;
        *(bf16x8*)(ob + (size_t)3 * S_LEN + tbase) = fr3;
    }
}

// ---------------- kernel 3: GEMM2  G[b][p][e] = sum_t wsT[b][p][t]*seqtH[b][e][t]
__global__ __launch_bounds__(256, 1) void k_gemm2(
    const bf16* __restrict__ wsT, const bf16* __restrict__ seqtH,
    float* __restrict__ outp)
{
    const int tid = threadIdx.x;
    const int wid = tid >> 6;
    const int lane = tid & 63;
    const int lr = lane & 15, lg = lane >> 4;
    const int bid = blockIdx.x;
    const int b = bid >> 3;
    const int sub = bid & 7;
    const int p0 = (sub >> 2) << 7;
    const int e0 = (sub & 3) << 7;

    const bf16* ap0 = wsT + ((size_t)b * NP + p0 + wid * 32 + lr) * S_LEN + lg * 8;
    const bf16* ap1 = ap0 + (size_t)16 * S_LEN;
    const bf16* bp  = seqtH + ((size_t)b * NE + e0 + lr) * S_LEN + lg * 8;

    f32x4 acc[2][8];
#pragma unroll
    for (int i = 0; i < 2; ++i)
#pragma unroll
        for (int j = 0; j < 8; ++j) acc[i][j] = (f32x4)(0.f);

#pragma unroll 2
    for (int kt = 0; kt < 64; ++kt) {
        const int k0 = kt * 32;
        const bf16x8 a0 = *(const bf16x8*)(ap0 + k0);
        const bf16x8 a1 = *(const bf16x8*)(ap1 + k0);
#pragma unroll
        for (int j = 0; j < 8; ++j) {
            const bf16x8 bv = *(const bf16x8*)(bp + (size_t)j * 16 * S_LEN + k0);
            acc[0][j] = __builtin_amdgcn_mfma_f32_16x16x32_bf16(a0, bv, acc[0][j], 0, 0, 0);
            acc[1][j] = __builtin_amdgcn_mfma_f32_16x16x32_bf16(a1, bv, acc[1][j], 0, 0, 0);
        }
    }
    float* obp = outp + ((size_t)b * NP + p0 + wid * 32) * NE + e0;
#pragma unroll
    for (int i = 0; i < 2; ++i)
#pragma unroll
        for (int j = 0; j < 8; ++j)
#pragma unroll
            for (int q = 0; q < 4; ++q)
                obp[(size_t)(i * 16 + lg * 4 + q) * NE + j * 16 + lr] = acc[i][j][q];
}

// ---------------- launch ----------------------------------------------------
extern "C" void kernel_launch(void* const* d_in, const int* in_sizes, int n_in,
                              void* d_out, int out_size, void* d_ws, size_t ws_size,
                              hipStream_t stream) {
    (void)in_sizes; (void)n_in; (void)out_size; (void)ws_size;
    const float* seq = (const float*)d_in[0];
    const float* w1  = (const float*)d_in[1];
    const float* b1  = (const float*)d_in[2];
    const float* w2  = (const float*)d_in[3];
    const float* b2  = (const float*)d_in[4];
    float* outp = (float*)d_out;

    char* ws = (char*)d_ws;
    bf16*  seqtH   = (bf16*)(ws);                        // 64 MB [b][e][s] bf16 hi
    bf16*  wsT     = (bf16*)(ws + (64ull << 20));        // 32 MB [b][p][t] bf16
    float* actions = (float*)(ws + (96ull << 20));       // 1 MB  [b*S][4] fp32
    bf16*  w1H     = (bf16*)(ws + (97ull << 20));        // 512 KB
    bf16*  w1L     = (bf16*)(ws + (97ull << 20) + (512u << 10)); // 512 KB

    hipLaunchKernelGGL(k_prep,  dim3(8192), dim3(256), 0, stream, seq, seqtH);
    hipLaunchKernelGGL(k_wconv, dim3(256),  dim3(256), 0, stream, w1, w1H, w1L);
    hipLaunchKernelGGL(k_gemm1, dim3(512),  dim3(256), 0, stream,
                       seq, w1H, w1L, b1, w2, b2, actions);
    hipLaunchKernelGGL(k_scan,  dim3(32),   dim3(64),  0, stream, actions, wsT);
    hipLaunchKernelGGL(k_gemm2, dim3(256),  dim3(256), 0, stream, wsT, seqtH, outp);
}

// Round 3
// 400.378 us; speedup vs baseline: 1.6319x; 1.6319x over previous
//
#include <hip/hip_runtime.h>
#include <stdint.h>

#define S_LEN 2048
#define NB 32
#define NE 512
#define NU 512
#define NP 256

typedef __bf16 bf16;
typedef __bf16 bf16x8 __attribute__((ext_vector_type(8)));
typedef __bf16 bf16x4 __attribute__((ext_vector_type(4)));
typedef float f32x4 __attribute__((ext_vector_type(4)));
typedef float f32x8 __attribute__((ext_vector_type(8)));

__device__ __forceinline__ void gload16(const void* g, void* l) {
    __builtin_amdgcn_global_load_lds(
        (__attribute__((address_space(1))) void*)g,
        (__attribute__((address_space(3))) void*)l, 16, 0, 0);
}

// Stage a 128-row x 32-col bf16 tile (row stride SR elems) into an 8KB LDS
// buffer, 2 chunks per thread. LDS chunk c holds row c>>2, k-quad
// q = (c&3) ^ ((c>>3)&3)  (self-inverse permutation; the matching ds_read
// applies the same XOR -> roundtrip identity, 2-way bank spread = free).
__device__ __forceinline__ void stage_tile(const bf16* __restrict__ src, int SR,
                                           bf16* lds, int tid) {
#pragma unroll
    for (int rnd = 0; rnd < 2; ++rnd) {
        const int c = rnd * 256 + tid;   // = (rnd*256 + wid*64) [uniform] + lane
        const int row = c >> 2;
        const int q = (c & 3) ^ ((c >> 3) & 3);
        gload16(src + (size_t)row * SR + q * 8, lds + c * 8);
    }
}

// ---------------- kernel 0a: seq[b][s][e] fp32 -> seqtH[b][e][s] bf16(hi) --
__global__ __launch_bounds__(256) void k_prep(
    const float* __restrict__ seq, bf16* __restrict__ tHi)
{
    __shared__ float tile[64][65];
    const int bid = blockIdx.x;
    const int b = bid >> 8;
    const int r = bid & 255;
    const int s0 = (r & 31) << 6;
    const int e0 = (r >> 5) << 6;
    const int t = threadIdx.x;
    const int tx = t & 15, ty = t >> 4;
    const float* src = seq + ((size_t)b * S_LEN + s0) * NE + e0;
#pragma unroll
    for (int i = 0; i < 4; ++i) {
        const int row = ty + i * 16;
        const float4 v = *(const float4*)(src + (size_t)row * NE + tx * 4);
        tile[row][tx * 4 + 0] = v.x; tile[row][tx * 4 + 1] = v.y;
        tile[row][tx * 4 + 2] = v.z; tile[row][tx * 4 + 3] = v.w;
    }
    __syncthreads();
    const int sx = t & 7, ey = t >> 3;
#pragma unroll
    for (int jj = 0; jj < 2; ++jj) {
        const int er = ey + jj * 32;
        bf16x8 oh;
#pragma unroll
        for (int q = 0; q < 8; ++q) oh[q] = (bf16)tile[sx * 8 + q][er];
        *(bf16x8*)(tHi + ((size_t)b * NE + e0 + er) * S_LEN + s0 + sx * 8) = oh;
    }
}

// ---------------- kernel 0b: w1 fp32 -> bf16 hi/lo --------------------------
__global__ __launch_bounds__(256) void k_wconv(
    const float* __restrict__ w1, bf16* __restrict__ wHi, bf16* __restrict__ wLo)
{
    const int i = (blockIdx.x * 256 + threadIdx.x) * 4;
    const float4 v = *(const float4*)(w1 + i);
    const float vv[4] = {v.x, v.y, v.z, v.w};
    bf16x4 oh, ol;
#pragma unroll
    for (int q = 0; q < 4; ++q) {
        const bf16 hb = (bf16)vv[q];
        oh[q] = hb;
        ol[q] = (bf16)(vv[q] - (float)hb);
    }
    *(bf16x4*)(wHi + i) = oh;
    *(bf16x4*)(wLo + i) = ol;
}

// ---------------- kernel 1: GEMM1 + silu + logits + softmax -----------------
// A = seq fp32 direct per-lane, hi/lo split in regs. B = w1 hi/lo staged in
// LDS (double-buffered global_load_lds), shared by the 4 waves.
__global__ __launch_bounds__(256, 2) void k_gemm1(
    const float* __restrict__ seq,
    const bf16* __restrict__ w1H, const bf16* __restrict__ w1L,
    const float* __restrict__ b1v, const float* __restrict__ w2,
    const float* __restrict__ b2v, float* __restrict__ actions)
{
    __shared__ __align__(16) bf16 BhL[2][4096];
    __shared__ __align__(16) bf16 BlL[2][4096];
    const int tid = threadIdx.x;
    const int wid = tid >> 6;
    const int lane = tid & 63;
    const int lr = lane & 15, lg = lane >> 4;
    const int m0 = blockIdx.x << 7;

    const float* arow0 = seq + (size_t)(m0 + wid * 32 + lr) * NE + lg * 8;
    const float* arow1 = arow0 + 16 * NE;
    const int lroff = lr * 64 + (lg ^ ((lr >> 1) & 3)) * 16;  // frag byte offset

    float plog[3][2][4];
#pragma unroll
    for (int a = 0; a < 3; ++a)
#pragma unroll
        for (int i = 0; i < 2; ++i)
#pragma unroll
            for (int q = 0; q < 4; ++q) plog[a][i][q] = 0.f;

    f32x4 acc[2][8];
    // prologue: stage g=0 (panel 0, kt 0) + A(g=0)
    stage_tile(w1H, NE, BhL[0], tid);
    stage_tile(w1L, NE, BlL[0], tid);
    f32x8 Aa0 = *(const f32x8*)(arow0);
    f32x8 Aa1 = *(const f32x8*)(arow1);
    f32x8 Ab0, Ab1;

#define G1_BODY(g, buf, Ac0, Ac1, An0, An1) do {                              \
        __syncthreads();   /* compiler drains vmcnt/lgkm: stage(g)+A ready */ \
        if (((g) & 15) == 0) {                                                \
            _Pragma("unroll") for (int i = 0; i < 2; ++i)                     \
            _Pragma("unroll") for (int j = 0; j < 8; ++j)                     \
                acc[i][j] = (f32x4)(0.f);                                     \
        }                                                                     \
        bf16x8 bh[8], bl[8];                                                  \
        _Pragma("unroll") for (int j = 0; j < 8; ++j) {                       \
            bh[j] = *(const bf16x8*)((const char*)BhL[buf] + j * 1024 + lroff);\
            bl[j] = *(const bf16x8*)((const char*)BlL[buf] + j * 1024 + lroff);\
        }                                                                     \
        __syncthreads();   /* all waves done reading buf */                   \
        if ((g) < 63) {                                                       \
            const int gn = (g) + 1;                                           \
            const int u0n = (gn >> 4) << 7;                                   \
            const int k0n = (gn & 15) << 5;                                   \
            stage_tile(w1H + (size_t)u0n * NE + k0n, NE, BhL[(buf) ^ 1], tid);\
            stage_tile(w1L + (size_t)u0n * NE + k0n, NE, BlL[(buf) ^ 1], tid);\
            An0 = *(const f32x8*)(arow0 + k0n);                               \
            An1 = *(const f32x8*)(arow1 + k0n);                               \
        }                                                                     \
        bf16x8 Ah0, Al0, Ah1, Al1;                                            \
        _Pragma("unroll") for (int q = 0; q < 8; ++q) {                       \
            const bf16 h0 = (bf16)Ac0[q];                                     \
            Ah0[q] = h0; Al0[q] = (bf16)(Ac0[q] - (float)h0);                 \
            const bf16 h1 = (bf16)Ac1[q];                                     \
            Ah1[q] = h1; Al1[q] = (bf16)(Ac1[q] - (float)h1);                 \
        }                                                                     \
        _Pragma("unroll") for (int j = 0; j < 8; ++j) {                       \
            acc[0][j] = __builtin_amdgcn_mfma_f32_16x16x32_bf16(Ah0, bh[j], acc[0][j], 0, 0, 0); \
            acc[0][j] = __builtin_amdgcn_mfma_f32_16x16x32_bf16(Ah0, bl[j], acc[0][j], 0, 0, 0); \
            acc[0][j] = __builtin_amdgcn_mfma_f32_16x16x32_bf16(Al0, bh[j], acc[0][j], 0, 0, 0); \
            acc[1][j] = __builtin_amdgcn_mfma_f32_16x16x32_bf16(Ah1, bh[j], acc[1][j], 0, 0, 0); \
            acc[1][j] = __builtin_amdgcn_mfma_f32_16x16x32_bf16(Ah1, bl[j], acc[1][j], 0, 0, 0); \
            acc[1][j] = __builtin_amdgcn_mfma_f32_16x16x32_bf16(Al1, bh[j], acc[1][j], 0, 0, 0); \
        }                                                                     \
        if (((g) & 15) == 15) {                                               \
            const int u0 = ((g) >> 4) << 7;                                   \
            _Pragma("unroll") for (int j = 0; j < 8; ++j) {                   \
                const int col = u0 + j * 16 + lr;                             \
                const float b1c = b1v[col];                                   \
                const float w20 = w2[col], w21 = w2[NU + col], w22 = w2[2 * NU + col]; \
                _Pragma("unroll") for (int i = 0; i < 2; ++i)                 \
                _Pragma("unroll") for (int q = 0; q < 4; ++q) {               \
                    const float x = acc[i][j][q] + b1c;                       \
                    const float hgate = x / (1.f + __expf(-x));               \
                    plog[0][i][q] = fmaf(hgate, w20, plog[0][i][q]);          \
                    plog[1][i][q] = fmaf(hgate, w21, plog[1][i][q]);          \
                    plog[2][i][q] = fmaf(hgate, w22, plog[2][i][q]);          \
                }                                                             \
            }                                                                 \
        }                                                                     \
    } while (0)

    for (int gg = 0; gg < 32; ++gg) {
        G1_BODY(2 * gg, 0, Aa0, Aa1, Ab0, Ab1);
        G1_BODY(2 * gg + 1, 1, Ab0, Ab1, Aa0, Aa1);
    }
#undef G1_BODY

#pragma unroll
    for (int m = 1; m < 16; m <<= 1) {
#pragma unroll
        for (int a = 0; a < 3; ++a)
#pragma unroll
            for (int i = 0; i < 2; ++i)
#pragma unroll
                for (int q = 0; q < 4; ++q)
                    plog[a][i][q] += __shfl_xor(plog[a][i][q], m);
    }
    const float bb0 = b2v[0], bb1 = b2v[1], bb2 = b2v[2];
    if (lr == 0) {
#pragma unroll
        for (int i = 0; i < 2; ++i)
#pragma unroll
            for (int q = 0; q < 4; ++q) {
                const int row = m0 + wid * 32 + i * 16 + lg * 4 + q;
                const float l0 = plog[0][i][q] + bb0;
                const float l1 = plog[1][i][q] + bb1;
                const float l2 = plog[2][i][q] + bb2;
                const float mx = fmaxf(l0, fmaxf(l1, l2));
                const float e0 = __expf(l0 - mx), e1 = __expf(l1 - mx), e2 = __expf(l2 - mx);
                const float inv = 1.f / (e0 + e1 + e2);
                *(float4*)(actions + (size_t)row * 4) = make_float4(e0 * inv, e1 * inv, e2 * inv, 0.f);
            }
    }
}

// ---------------- kernel 2: sequential scan, writes wsT[b][p][t] bf16 -------
// lane = wq*16 + h  (h = lane&15, wq = lane>>4); lane owns w = wq*4+c, c=0..3.
// rs[h-1] via DPP row_shr:1 (VALU-speed, on the critical chain);
// T0[w+1] (= lane+16) via shfl_down pipelined across the 1-step window.
__global__ __launch_bounds__(64) void k_scan(
    const float* __restrict__ actions, bf16* __restrict__ wsT)
{
    const int b = blockIdx.x;
    const int lane = threadIdx.x;
    const int h = lane & 15;
    const int wq = lane >> 4;
    float T0 = 0.f, T1 = 0.f, T2 = 0.f, T3 = 0.f;
    if (lane == 48) T3 = 1.f;          // (h=0, wq=3, c=3) -> T[b][0][15] = 1
    float rs = (h == 0) ? 1.f : 0.f;
    const float4* act = (const float4*)actions + (size_t)b * S_LEN;
    bf16* ob = wsT + ((size_t)b * NP + h * 16 + wq * 4) * S_LEN;

    float nT0 = __shfl_down(T0, 16);   // T0 of (wq+1, h) for current state

    for (int s4 = 0; s4 < S_LEN; s4 += 8) {
        const int tbase = S_LEN - 8 - s4;
        bf16x8 fr0, fr1, fr2, fr3;
#pragma unroll
        for (int u = 0; u < 8; ++u) {
            const float4 Av = act[tbase + 7 - u];
            const float a0 = Av.x, a1 = Av.y, a2 = Av.z;
            const float s01 = a0 + a1;
            const int fi = 7 - u;
            fr0[fi] = (bf16)(s01 * T0);
            fr1[fi] = (bf16)(s01 * T1);
            fr2[fi] = (bf16)(s01 * T2);
            fr3[fi] = (bf16)(s01 * T3);
            // rs[h-1]: DPP row_shr:1, bound_ctrl -> 0 at h==0
            const int rsi = __builtin_amdgcn_update_dpp(
                0, __builtin_bit_cast(int, rs), 0x111, 0xF, 0xF, true);
            const float rsp = __builtin_bit_cast(float, rsi);
            const float sums = a1 * rsp;
            const float q1 = a0 * T1, q2 = a0 * T2, q3 = a0 * T3;
            const float qe = (wq == 3) ? sums : a0 * nT0;
            T0 = fmaf(a2, T0, q1);
            T1 = fmaf(a2, T1, q2);
            T2 = fmaf(a2, T2, q3);
            T3 = fmaf(a2, T3, qe);
            rs = fmaf(a0 + a2, rs, sums);
            nT0 = __shfl_down(T0, 16);   // for next step (1-step latency window)
        }
        *(bf16x8*)(ob + (size_t)0 * S_LEN + tbase) = fr0;
        *(bf16x8*)(ob + (size_t)1 * S_LEN + tbase) = fr1;
        *(bf16x8*)(ob + (size_t)2 * S_LEN + tbase) = fr2;
        *(bf16x8*)(ob + (size_t)3 * S_LEN + tbase) = fr3;
    }
}

// ---------------- kernel 3: GEMM2 partials (2-way k-split, LDS-staged) ------
// part[kc][b][p][e] = sum_{t in chunk kc} wsT[b][p][t] * seqtH[b][e][t]
__global__ __launch_bounds__(256, 2) void k_gemm2(
    const bf16* __restrict__ wsT, const bf16* __restrict__ seqtH,
    float* __restrict__ part)
{
    __shared__ __align__(16) bf16 AL[2][4096];
    __shared__ __align__(16) bf16 BL[2][4096];
    const int tid = threadIdx.x;
    const int wid = tid >> 6;
    const int lane = tid & 63;
    const int lr = lane & 15, lg = lane >> 4;
    const int bid = blockIdx.x;
    const int b = bid >> 4;
    const int sub = bid & 15;
    const int kc = sub >> 3;
    const int p0 = ((sub >> 2) & 1) << 7;
    const int e0 = (sub & 3) << 7;

    const bf16* Abase = wsT + ((size_t)b * NP + p0) * S_LEN + kc * 1024;
    const bf16* Bbase = seqtH + ((size_t)b * NE + e0) * S_LEN + kc * 1024;
    const int lroff = lr * 64 + (lg ^ ((lr >> 1) & 3)) * 16;

    f32x4 acc[2][8];
#pragma unroll
    for (int i = 0; i < 2; ++i)
#pragma unroll
        for (int j = 0; j < 8; ++j) acc[i][j] = (f32x4)(0.f);

    stage_tile(Abase, S_LEN, AL[0], tid);
    stage_tile(Bbase, S_LEN, BL[0], tid);

#define G2_BODY(kt, buf) do {                                                 \
        __syncthreads();                                                      \
        bf16x8 af[2], bfv[8];                                                 \
        _Pragma("unroll") for (int i = 0; i < 2; ++i)                         \
            af[i] = *(const bf16x8*)((const char*)AL[buf]                     \
                     + (wid * 32 + i * 16) * 64 + lroff);                     \
        _Pragma("unroll") for (int j = 0; j < 8; ++j)                         \
            bfv[j] = *(const bf16x8*)((const char*)BL[buf] + j * 1024 + lroff);\
        __syncthreads();                                                      \
        if ((kt) < 31) {                                                      \
            stage_tile(Abase + ((kt) + 1) * 32, S_LEN, AL[(buf) ^ 1], tid);   \
            stage_tile(Bbase + ((kt) + 1) * 32, S_LEN, BL[(buf) ^ 1], tid);   \
        }                                                                     \
        _Pragma("unroll") for (int j = 0; j < 8; ++j) {                       \
            acc[0][j] = __builtin_amdgcn_mfma_f32_16x16x32_bf16(af[0], bfv[j], acc[0][j], 0, 0, 0); \
            acc[1][j] = __builtin_amdgcn_mfma_f32_16x16x32_bf16(af[1], bfv[j], acc[1][j], 0, 0, 0); \
        }                                                                     \
    } while (0)

    for (int kk = 0; kk < 16; ++kk) {
        G2_BODY(2 * kk, 0);
        G2_BODY(2 * kk + 1, 1);
    }
#undef G2_BODY

    float* obp = part + (((size_t)kc * NB + b) * NP + p0 + wid * 32) * NE + e0;
#pragma unroll
    for (int i = 0; i < 2; ++i)
#pragma unroll
        for (int j = 0; j < 8; ++j)
#pragma unroll
            for (int q = 0; q < 4; ++q)
                obp[(size_t)(i * 16 + lg * 4 + q) * NE + j * 16 + lr] = acc[i][j][q];
}

// ---------------- kernel 4: reduce the 2 partials ---------------------------
__global__ __launch_bounds__(256) void k_gred(
    const float* __restrict__ part, float* __restrict__ outp)
{
    const size_t i = ((size_t)blockIdx.x * 256 + threadIdx.x) * 4;
    const float4 p0 = *(const float4*)(part + i);
    const float4 p1 = *(const float4*)(part + ((size_t)NB * NP * NE) + i);
    *(float4*)(outp + i) = make_float4(p0.x + p1.x, p0.y + p1.y,
                                       p0.z + p1.z, p0.w + p1.w);
}

// ---------------- launch ----------------------------------------------------
extern "C" void kernel_launch(void* const* d_in, const int* in_sizes, int n_in,
                              void* d_out, int out_size, void* d_ws, size_t ws_size,
                              hipStream_t stream) {
    (void)in_sizes; (void)n_in; (void)out_size; (void)ws_size;
    const float* seq = (const float*)d_in[0];
    const float* w1  = (const float*)d_in[1];
    const float* b1  = (const float*)d_in[2];
    const float* w2  = (const float*)d_in[3];
    const float* b2  = (const float*)d_in[4];
    float* outp = (float*)d_out;

    char* ws = (char*)d_ws;
    bf16*  seqtH   = (bf16*)(ws);                        // 64 MB [b][e][s]
    bf16*  wsT     = (bf16*)(ws + (64ull << 20));        // 32 MB [b][p][t]
    float* actions = (float*)(ws + (96ull << 20));       // 1 MB  [b*S][4]
    bf16*  w1H     = (bf16*)(ws + (97ull << 20));        // 512 KB
    bf16*  w1L     = (bf16*)(ws + (97ull << 20) + (512u << 10)); // 512 KB
    float* part    = (float*)(ws + (98ull << 20));       // 32 MB [2][b][p][e]

    hipLaunchKernelGGL(k_prep,  dim3(8192), dim3(256), 0, stream, seq, seqtH);
    hipLaunchKernelGGL(k_wconv, dim3(256),  dim3(256), 0, stream, w1, w1H, w1L);
    hipLaunchKernelGGL(k_gemm1, dim3(512),  dim3(256), 0, stream,
                       seq, w1H, w1L, b1, w2, b2, actions);
    hipLaunchKernelGGL(k_scan,  dim3(32),   dim3(64),  0, stream, actions, wsT);
    hipLaunchKernelGGL(k_gemm2, dim3(512),  dim3(256), 0, stream, wsT, seqtH, part);
    hipLaunchKernelGGL(k_gred,  dim3(4096), dim3(256), 0, stream, part, outp);
}